// Round 18
// baseline (390.908 us; speedup 1.0000x reference)
//
#include <hip/hip_runtime.h>
#include <math.h>

// ---------------------------------------------------------------------------
// I2HOFI forward. B=8, 13 ROI graphs x 392 nodes (intra) / 392 x 13 (inter),
// feature 256. Weight GEMMs: 128x128 LDS-tiled bf16 MFMA, K=256, BK=32,
// double-buffered LDS (1 barrier/K-step) + 2-deep register prefetch.
// Pool: dedicated 256x128-tile kernel (2 A row-tiles share each B tile:
// -25% LDS traffic per FLOP). Intra GAT: separable leaky-softmax O(N*d).
// Node row layout: row = (b*13 + r)*392 + c.
// x2 rows padded per (branch,b) segment: seg*5120 + within (within < 5096).
// ---------------------------------------------------------------------------

typedef __attribute__((ext_vector_type(8))) short bf16x8;
typedef __attribute__((ext_vector_type(4))) float f32x4;

#define MFMA16x32(a, b, c) __builtin_amdgcn_mfma_f32_16x16x32_bf16((a), (b), (c), 0, 0, 0)

__device__ __forceinline__ float sigmoidf_(float x) { return 1.0f / (1.0f + __expf(-x)); }
__device__ __forceinline__ float leakyf_(float x) { return x >= 0.0f ? x : 0.2f * x; }
__device__ __forceinline__ float eluf_(float x) { return x > 0.0f ? x : __expf(x) - 1.0f; }
__device__ __forceinline__ short f2bf(float f) {
  unsigned u = __builtin_bit_cast(unsigned, f);
  unsigned r = u + 0x7fffu + ((u >> 16) & 1u);
  return (short)(r >> 16);
}
__device__ __forceinline__ float bf2f(short s) {
  unsigned u = ((unsigned)(unsigned short)s) << 16;
  return __builtin_bit_cast(float, u);
}
__device__ __forceinline__ f32x4 fzero4() {
  f32x4 z;
  #pragma unroll
  for (int i = 0; i < 4; ++i) z[i] = 0.0f;
  return z;
}

// --------------------------------------------------------------------------
// prep_k: all weight preprocessing in ONE dispatch.
// --------------------------------------------------------------------------
__global__ __launch_bounds__(256) void prep_k(
    const float* __restrict__ appnp_w, const float* __restrict__ gat_k,
    const float* __restrict__ pf_w, const float* __restrict__ pa_w,
    const float* __restrict__ gat_as, const float* __restrict__ gat_an,
    short* __restrict__ aWhi, short* __restrict__ gkhi,
    short* __restrict__ pwcomb, float* __restrict__ wtab,
    float* __restrict__ was, float* __restrict__ wan) {
  const int bx = blockIdx.x;
  const int tid = threadIdx.x;
  if (bx < 512) {
    const int idx = (bx & 255) * 256 + tid;
    const int k = idx >> 8, n = idx & 255;
    const float* src = (bx < 256) ? appnp_w : gat_k;
    short* dst = (bx < 256) ? aWhi : gkhi;
    dst[(size_t)n * 256 + k] = f2bf(src[(size_t)k * 256 + n]);
  } else if (bx < 1536) {
    const int idx = (bx - 512) * 256 + tid;
    const int n = idx >> 8, k = idx & 255;
    const int p = n >> 4, i = n & 15;
    const int sc = ((p >> 1) << 4) + i;
    const float v = (p & 1) ? pa_w[(size_t)k * 512 + sc] : pf_w[(size_t)k * 512 + sc];
    pwcomb[(size_t)n * 256 + k] = f2bf(v);
  } else if (bx == 1536) {
    const int RX[12] = {0,14,28, 0,14,28, 0,14,28, 0, 0, 0};
    const int RY[12] = {0, 0, 0,14,14,14,28,28,28, 0,21, 0};
    const int RW[12] = {14,14,14,14,14,14,14,14,14,42,42,42};
    const int RH[12] = {14,14,14,14,14,14,14,14,14,21,21,42};
    for (int e = tid; e < 13 * 2 * 49; e += 256) {
      const int roi = e / 98;
      const int rest = e % 98;
      const int axis = rest / 49;
      const int o = (rest % 49) / 7;
      const int ib = rest % 7;
      float wout;
      if (roi == 12) {
        wout = (o == ib) ? 1.0f : 0.0f;
      } else {
        const int start = axis ? RX[roi] : RY[roi];
        const int len = axis ? RW[roi] : RH[roi];
        const float s = (float)len / 7.0f;
        const float oc = (o + 0.5f) * s - 0.5f;
        float wsum = 0.0f, dot = 0.0f;
        for (int j = 0; j < len; ++j) {
          float w = 1.0f - fabsf((float)j - oc) / s;
          if (w <= 0.0f) continue;
          wsum += w;
          const float ic = ((float)(start + j) + 0.5f) / 6.0f - 0.5f;
          const float fl = floorf(ic);
          const int ia = (int)fl;
          const float fr = ic - fl;
          int c0 = ia;     if (c0 < 0) c0 = 0; if (c0 > 6) c0 = 6;
          int c1 = ia + 1; if (c1 < 0) c1 = 0; if (c1 > 6) c1 = 6;
          float u = 0.0f;
          if (c0 == ib) u += 1.0f - fr;
          if (c1 == ib) u += fr;
          dot += w * u;
        }
        wout = dot / wsum;
      }
      wtab[e] = wout;
    }
  } else {
    const int w = tid >> 6, l = tid & 63;
    const int row = (bx - 1537) * 4 + w;
    const float* p = gat_k + (size_t)row * 256;
    float s = 0.0f, t = 0.0f;
    #pragma unroll
    for (int j = 0; j < 4; ++j) {
      const int o = l + j * 64;
      const float v = p[o];
      s = fmaf(v, gat_as[o], s);
      t = fmaf(v, gat_an[o], t);
    }
    #pragma unroll
    for (int off = 32; off; off >>= 1) { s += __shfl_down(s, off); t += __shfl_down(t, off); }
    if (l == 0) { was[row] = s; wan[row] = t; }
  }
}

// --------------------------------------------------------------------------
// K1: nodes (bf16) via separable 49x49 resize contraction.
// --------------------------------------------------------------------------
__global__ __launch_bounds__(256) void nodes_k(const float* __restrict__ base,
                                               const float* __restrict__ wtab,
                                               short* __restrict__ nodes) {
  const int blk = blockIdx.x;
  const int chunk = blk & 7;
  const int br = blk >> 3;
  const int r = br % 13;
  const int b = br / 13;
  const int f = threadIdx.x;
  __shared__ float W49[49][50];
  const float* wv = wtab + (r * 2 + 0) * 49;
  const float* wh = wtab + (r * 2 + 1) * 49;
  for (int e = f; e < 2401; e += 256) {
    const int o = e / 49, in = e % 49;
    W49[o][in] = wv[(o / 7) * 7 + in / 7] * wh[(o % 7) * 7 + in % 7];
  }
  __syncthreads();
  float bv[49];
  const float* bp = base + (size_t)b * 49 * 2048 + chunk * 256 + f;
  #pragma unroll
  for (int in = 0; in < 49; ++in) bv[in] = bp[(size_t)in * 2048];
  const size_t obase = ((size_t)(b * 13 + r) * 392 + chunk * 49) * 256 + f;
  for (int o = 0; o < 49; ++o) {
    float acc = 0.0f;
    #pragma unroll
    for (int in = 0; in < 49; ++in) acc = fmaf(W49[o][in], bv[in], acc);
    nodes[obase + (size_t)o * 256] = f2bf(acc);
  }
}

// --------------------------------------------------------------------------
// Tiled MFMA GEMM: 128x128 tile, K=256 (8 steps of BK=32), 4 waves (2x2).
// Double-buffered LDS, ONE barrier per K-step, register prefetch distance 2.
// Epilogues: PLAIN (2-segment via segRows) / SIG.
// --------------------------------------------------------------------------
enum { EP_PLAIN = 0, EP_SIG = 1 };

template <int EPI>
__global__ __launch_bounds__(256) void gemm_t(
    const short* __restrict__ A, const short* __restrict__ BT,
    const int Mvalid, const int segRows,
    const float* __restrict__ e0,
    short* __restrict__ Cs) {
  const int tid = threadIdx.x;
  const int w = tid >> 6, l = tid & 63;
  const int lr = l & 15, kb = l >> 4;
  const int wr = w >> 1, wc = w & 1;

  const int row0 = blockIdx.x * 128, col0 = blockIdx.y * 128;

  __shared__ short As[2][128][32];
  __shared__ short Bs[2][128][32];

  const int srow = w * 32 + (l >> 2);
  const int sso = (l & 3) * 8;
  const short* ag0 = A + (size_t)(row0 + srow) * 256 + sso;
  const short* ag1 = ag0 + (size_t)16 * 256;
  const short* bg0 = BT + (size_t)(col0 + srow) * 256 + sso;
  const short* bg1 = bg0 + (size_t)16 * 256;

  f32x4 acc[4][4];
  #pragma unroll
  for (int i = 0; i < 4; ++i)
    #pragma unroll
    for (int j = 0; j < 4; ++j) acc[i][j] = fzero4();

  auto compute = [&](const short (*Ab)[32], const short (*Bb)[32]) {
    bf16x8 va[4], vb[4];
    #pragma unroll
    for (int i = 0; i < 4; ++i) va[i] = *(const bf16x8*)&Ab[wr * 64 + i * 16 + lr][kb * 8];
    #pragma unroll
    for (int j = 0; j < 4; ++j) vb[j] = *(const bf16x8*)&Bb[wc * 64 + j * 16 + lr][kb * 8];
    #pragma unroll
    for (int i = 0; i < 4; ++i)
      #pragma unroll
      for (int j = 0; j < 4; ++j) acc[i][j] = MFMA16x32(va[i], vb[j], acc[i][j]);
  };

  bf16x8 eA0, eA1, eB0, eB1, oA0, oA1, oB0, oB1;
  eA0 = *(const bf16x8*)(ag0);       eA1 = *(const bf16x8*)(ag1);
  eB0 = *(const bf16x8*)(bg0);       eB1 = *(const bf16x8*)(bg1);
  oA0 = *(const bf16x8*)(ag0 + 32);  oA1 = *(const bf16x8*)(ag1 + 32);
  oB0 = *(const bf16x8*)(bg0 + 32);  oB1 = *(const bf16x8*)(bg1 + 32);
  *(bf16x8*)&As[0][srow][sso] = eA0; *(bf16x8*)&As[0][srow + 16][sso] = eA1;
  *(bf16x8*)&Bs[0][srow][sso] = eB0; *(bf16x8*)&Bs[0][srow + 16][sso] = eB1;
  eA0 = *(const bf16x8*)(ag0 + 64);  eA1 = *(const bf16x8*)(ag1 + 64);
  eB0 = *(const bf16x8*)(bg0 + 64);  eB1 = *(const bf16x8*)(bg1 + 64);
  __syncthreads();

  #pragma unroll
  for (int kt = 0; kt < 8; kt += 2) {
    {
      *(bf16x8*)&As[1][srow][sso] = oA0; *(bf16x8*)&As[1][srow + 16][sso] = oA1;
      *(bf16x8*)&Bs[1][srow][sso] = oB0; *(bf16x8*)&Bs[1][srow + 16][sso] = oB1;
      if (kt + 3 < 8) {
        const int ko = (kt + 3) * 32;
        oA0 = *(const bf16x8*)(ag0 + ko); oA1 = *(const bf16x8*)(ag1 + ko);
        oB0 = *(const bf16x8*)(bg0 + ko); oB1 = *(const bf16x8*)(bg1 + ko);
      }
    }
    compute(As[0], Bs[0]);
    __syncthreads();
    if (kt + 2 < 8) {
      *(bf16x8*)&As[0][srow][sso] = eA0; *(bf16x8*)&As[0][srow + 16][sso] = eA1;
      *(bf16x8*)&Bs[0][srow][sso] = eB0; *(bf16x8*)&Bs[0][srow + 16][sso] = eB1;
      if (kt + 4 < 8) {
        const int ko = (kt + 4) * 32;
        eA0 = *(const bf16x8*)(ag0 + ko); eA1 = *(const bf16x8*)(ag1 + ko);
        eB0 = *(const bf16x8*)(bg0 + ko); eB1 = *(const bf16x8*)(bg1 + ko);
      }
    }
    compute(As[1], Bs[1]);
    __syncthreads();
  }

  #pragma unroll
  for (int j = 0; j < 4; ++j) {
    const int col = col0 + wc * 64 + j * 16 + lr;
    float bs = 0.0f;
    if constexpr (EPI == EP_SIG) bs = e0[col];
    #pragma unroll
    for (int i = 0; i < 4; ++i) {
      const int row = row0 + wr * 64 + i * 16 + kb * 4;
      #pragma unroll
      for (int r = 0; r < 4; ++r) {
        const int grow = row + r;
        const int lrow = (grow >= segRows) ? grow - segRows : grow;
        if (lrow < Mvalid) {
          float o = acc[i][j][r];
          if constexpr (EPI == EP_SIG) o = sigmoidf_(o + bs);
          Cs[(size_t)grow * 256 + col] = f2bf(o);
        }
      }
    }
  }
}

// --------------------------------------------------------------------------
// Pool GEMM: 256x128 tile (A0,A1 row-tiles share staged B: -25% LDS traffic
// per FLOP). Same dbuf/1-barrier/prefetch-2 schedule. grid 2560 (XCD swz).
// Epilogue: sigmoid(gate)*feat over both row-tiles -> one atomicAdd.
// --------------------------------------------------------------------------
__global__ __launch_bounds__(256) void pool2_k(
    const short* __restrict__ A, const short* __restrict__ BT,
    const float* __restrict__ e0, const float* __restrict__ e1,
    float* __restrict__ xf) {
  const int tid = threadIdx.x;
  const int w = tid >> 6, l = tid & 63;
  const int lr = l & 15, kb = l >> 4;
  const int wr = w >> 1, wc = w & 1;

  const int bid = blockIdx.x;
  const int eff = (bid & 7) * 320 + (bid >> 3);    // XCD-chunked swizzle
  const int mt2 = eff >> 3, ct = eff & 7;
  const int row0 = mt2 * 256, col0 = ct * 128;
  const int rbase = (mt2 % 20) * 256;
  const int bseg = (mt2 / 20) & 7;

  __shared__ short As0[2][128][32];
  __shared__ short As1[2][128][32];
  __shared__ short Bs[2][128][32];

  const int srow = w * 32 + (l >> 2);
  const int sso = (l & 3) * 8;
  const short* a0g0 = A + (size_t)(row0 + srow) * 256 + sso;
  const short* a0g1 = a0g0 + (size_t)16 * 256;
  const short* a1g0 = A + (size_t)(row0 + 128 + srow) * 256 + sso;
  const short* a1g1 = a1g0 + (size_t)16 * 256;
  const short* bg0 = BT + (size_t)(col0 + srow) * 256 + sso;
  const short* bg1 = bg0 + (size_t)16 * 256;

  f32x4 acc0[4][4], acc1[4][4];
  #pragma unroll
  for (int i = 0; i < 4; ++i)
    #pragma unroll
    for (int j = 0; j < 4; ++j) { acc0[i][j] = fzero4(); acc1[i][j] = fzero4(); }

  auto compute = [&](const short (*A0b)[32], const short (*A1b)[32],
                     const short (*Bb)[32]) {
    bf16x8 va0[4], va1[4], vb[4];
    #pragma unroll
    for (int i = 0; i < 4; ++i) {
      va0[i] = *(const bf16x8*)&A0b[wr * 64 + i * 16 + lr][kb * 8];
      va1[i] = *(const bf16x8*)&A1b[wr * 64 + i * 16 + lr][kb * 8];
    }
    #pragma unroll
    for (int j = 0; j < 4; ++j) vb[j] = *(const bf16x8*)&Bb[wc * 64 + j * 16 + lr][kb * 8];
    #pragma unroll
    for (int i = 0; i < 4; ++i)
      #pragma unroll
      for (int j = 0; j < 4; ++j) {
        acc0[i][j] = MFMA16x32(va0[i], vb[j], acc0[i][j]);
        acc1[i][j] = MFMA16x32(va1[i], vb[j], acc1[i][j]);
      }
  };

  bf16x8 eA00, eA01, eA10, eA11, eB0, eB1;
  bf16x8 oA00, oA01, oA10, oA11, oB0, oB1;
  eA00 = *(const bf16x8*)(a0g0);      eA01 = *(const bf16x8*)(a0g1);
  eA10 = *(const bf16x8*)(a1g0);      eA11 = *(const bf16x8*)(a1g1);
  eB0  = *(const bf16x8*)(bg0);       eB1  = *(const bf16x8*)(bg1);
  oA00 = *(const bf16x8*)(a0g0 + 32); oA01 = *(const bf16x8*)(a0g1 + 32);
  oA10 = *(const bf16x8*)(a1g0 + 32); oA11 = *(const bf16x8*)(a1g1 + 32);
  oB0  = *(const bf16x8*)(bg0 + 32);  oB1  = *(const bf16x8*)(bg1 + 32);
  *(bf16x8*)&As0[0][srow][sso] = eA00; *(bf16x8*)&As0[0][srow + 16][sso] = eA01;
  *(bf16x8*)&As1[0][srow][sso] = eA10; *(bf16x8*)&As1[0][srow + 16][sso] = eA11;
  *(bf16x8*)&Bs[0][srow][sso]  = eB0;  *(bf16x8*)&Bs[0][srow + 16][sso]  = eB1;
  eA00 = *(const bf16x8*)(a0g0 + 64); eA01 = *(const bf16x8*)(a0g1 + 64);
  eA10 = *(const bf16x8*)(a1g0 + 64); eA11 = *(const bf16x8*)(a1g1 + 64);
  eB0  = *(const bf16x8*)(bg0 + 64);  eB1  = *(const bf16x8*)(bg1 + 64);
  __syncthreads();

  #pragma unroll
  for (int kt = 0; kt < 8; kt += 2) {
    {
      *(bf16x8*)&As0[1][srow][sso] = oA00; *(bf16x8*)&As0[1][srow + 16][sso] = oA01;
      *(bf16x8*)&As1[1][srow][sso] = oA10; *(bf16x8*)&As1[1][srow + 16][sso] = oA11;
      *(bf16x8*)&Bs[1][srow][sso]  = oB0;  *(bf16x8*)&Bs[1][srow + 16][sso]  = oB1;
      if (kt + 3 < 8) {
        const int ko = (kt + 3) * 32;
        oA00 = *(const bf16x8*)(a0g0 + ko); oA01 = *(const bf16x8*)(a0g1 + ko);
        oA10 = *(const bf16x8*)(a1g0 + ko); oA11 = *(const bf16x8*)(a1g1 + ko);
        oB0  = *(const bf16x8*)(bg0 + ko);  oB1  = *(const bf16x8*)(bg1 + ko);
      }
    }
    compute(As0[0], As1[0], Bs[0]);
    __syncthreads();
    if (kt + 2 < 8) {
      *(bf16x8*)&As0[0][srow][sso] = eA00; *(bf16x8*)&As0[0][srow + 16][sso] = eA01;
      *(bf16x8*)&As1[0][srow][sso] = eA10; *(bf16x8*)&As1[0][srow + 16][sso] = eA11;
      *(bf16x8*)&Bs[0][srow][sso]  = eB0;  *(bf16x8*)&Bs[0][srow + 16][sso]  = eB1;
      if (kt + 4 < 8) {
        const int ko = (kt + 4) * 32;
        eA00 = *(const bf16x8*)(a0g0 + ko); eA01 = *(const bf16x8*)(a0g1 + ko);
        eA10 = *(const bf16x8*)(a1g0 + ko); eA11 = *(const bf16x8*)(a1g1 + ko);
        eB0  = *(const bf16x8*)(bg0 + ko);  eB1  = *(const bf16x8*)(bg1 + ko);
      }
    }
    compute(As0[1], As1[1], Bs[1]);
    __syncthreads();
  }

  #pragma unroll
  for (int jp = 0; jp < 2; ++jp) {
    const int j = jp * 2;
    const int cg = col0 + wc * 64 + j * 16;          // feat group base
    const int realcol = ((cg >> 5) << 4) + lr;
    const float bfv = e0[realcol], bav = e1[realcol];
    float cs = 0.0f;
    #pragma unroll
    for (int i = 0; i < 4; ++i) {
      const int rl0 = rbase + wr * 64 + i * 16 + kb * 4;
      const int rl1 = rl0 + 128;
      #pragma unroll
      for (int r = 0; r < 4; ++r) {
        if (rl0 + r < 5096)
          cs += sigmoidf_(acc0[i][j + 1][r] + bav) * (acc0[i][j][r] + bfv);
        if (rl1 + r < 5096)
          cs += sigmoidf_(acc1[i][j + 1][r] + bav) * (acc1[i][j][r] + bfv);
      }
    }
    cs += __shfl_xor(cs, 16);
    cs += __shfl_xor(cs, 32);
    if (l < 16) atomicAdd(&xf[(size_t)bseg * 512 + realcol], cs);
  }
}

// --------------------------------------------------------------------------
// Intra GAT, separable leaky-softmax (exact fp32). A: per-graph setup.
// --------------------------------------------------------------------------
__global__ __launch_bounds__(256) void attn_setup_k(
    const float* __restrict__ sb, const float* __restrict__ tb,
    unsigned short* __restrict__ ord, float* __restrict__ usr,
    float* __restrict__ vsr, unsigned short* __restrict__ cN,
    float* __restrict__ a1, float* __restrict__ a2) {
  const int g = blockIdx.x;
  const int tid = threadIdx.x;
  __shared__ float t_s[392], s_s[392];
  __shared__ float u_r[392], v_r[392];
  __shared__ float pu_s[393], pv_s[393];
  __shared__ unsigned short cn_s[392];
  __shared__ float red[256];
  const size_t gb = (size_t)g * 392;
  for (int i = tid; i < 392; i += 256) {
    t_s[i] = tb[gb + i];
    s_s[i] = sb[gb + i];
  }
  __syncthreads();
  float lm = -1e30f;
  for (int i = tid; i < 392; i += 256) lm = fmaxf(lm, t_s[i]);
  red[tid] = lm;
  __syncthreads();
  for (int off = 128; off; off >>= 1) {
    if (tid < off) red[tid] = fmaxf(red[tid], red[tid + off]);
    __syncthreads();
  }
  const float tmax = red[0];
  for (int i = tid; i < 392; i += 256) {
    const float ti = t_s[i], si = s_s[i];
    int rt = 0, c = 0;
    for (int j = 0; j < 392; ++j) {
      const float tj = t_s[j];
      rt += (int)((tj < ti) | ((tj == ti) & (j < i)));
      c  += (int)(tj < -si);
    }
    const float u = __expf(ti - tmax);
    const float v = __expf(0.2f * (ti - tmax));
    u_r[rt] = u; v_r[rt] = v;
    ord[gb + rt] = (unsigned short)i;
    usr[gb + rt] = u; vsr[gb + rt] = v;
    cn_s[i] = (unsigned short)c;
    cN[gb + i] = (unsigned short)c;
  }
  __syncthreads();
  if (tid == 0) {
    float r1 = 0.0f, r2 = 0.0f;
    for (int k = 0; k < 392; ++k) {
      pu_s[k] = r1; pv_s[k] = r2;
      r1 += u_r[k]; r2 += v_r[k];
    }
    pu_s[392] = r1; pv_s[392] = r2;
  }
  __syncthreads();
  const float U1 = pu_s[392];
  for (int i = tid; i < 392; i += 256) {
    const float z = s_s[i] + tmax;
    const float c1 = (z < 0.0f) ? __expf(0.8f * z) : 1.0f;
    const float c2 = (z < 0.0f) ? 1.0f : __expf(-0.8f * z);
    const int c = cn_s[i];
    const float den = c1 * (U1 - pu_s[c]) + c2 * pv_s[c];
    a1[gb + i] = c1 / den;
    a2[gb + i] = c2 / den;
  }
}

// B: segment sums over 8-rank segments. grid (49, G), 256 threads = features.
__global__ __launch_bounds__(256) void attn_seg_k(
    const short* __restrict__ xp, const unsigned short* __restrict__ ord,
    const float* __restrict__ usr, const float* __restrict__ vsr,
    float* __restrict__ SS1, float* __restrict__ SS2) {
  const int g = blockIdx.y, s = blockIdx.x;
  const int f = threadIdx.x;
  const size_t gb = (size_t)g * 392;
  float acc1 = 0.0f, acc2 = 0.0f;
  #pragma unroll
  for (int k = 0; k < 8; ++k) {
    const int r = s * 8 + k;
    const int row = ord[gb + r];
    const float x = bf2f(xp[(gb + row) * 256 + f]);
    acc1 = fmaf(usr[gb + r], x, acc1);
    acc2 = fmaf(vsr[gb + r], x, acc2);
  }
  SS1[((size_t)g * 49 + s) * 256 + f] = acc1;
  SS2[((size_t)g * 49 + s) * 256 + f] = acc2;
}

// C: 49-step exclusive scan -> PS[0..49] (PS[49] = total). grid G.
__global__ __launch_bounds__(256) void attn_scan_k(
    const float* __restrict__ SS1, const float* __restrict__ SS2,
    float* __restrict__ PS1, float* __restrict__ PS2) {
  const int g = blockIdx.x;
  const int f = threadIdx.x;
  float r1 = 0.0f, r2 = 0.0f;
  for (int s = 0; s < 49; ++s) {
    PS1[((size_t)g * 50 + s) * 256 + f] = r1;
    PS2[((size_t)g * 50 + s) * 256 + f] = r2;
    r1 += SS1[((size_t)g * 49 + s) * 256 + f];
    r2 += SS2[((size_t)g * 49 + s) * 256 + f];
  }
  PS1[((size_t)g * 50 + 49) * 256 + f] = r1;
  PS2[((size_t)g * 50 + 49) * 256 + f] = r2;
}

// D: outputs. grid (49, G), block 256 = features; 8 outputs per block.
// Fine correction statically unrolled to 8 masked lanes.
__global__ __launch_bounds__(256) void attn_out_k(
    const short* __restrict__ xp, const unsigned short* __restrict__ ord,
    const float* __restrict__ usr, const float* __restrict__ vsr,
    const unsigned short* __restrict__ cN, const float* __restrict__ a1,
    const float* __restrict__ a2, const float* __restrict__ PS1,
    const float* __restrict__ PS2, const float* __restrict__ bias,
    const short* __restrict__ h, short* __restrict__ x2) {
  const int g = blockIdx.y, bx = blockIdx.x;
  const int f = threadIdx.x;
  const size_t gb = (size_t)g * 392;
  const int bb = g / 13, rr = g % 13;
  const float T1f = PS1[((size_t)g * 50 + 49) * 256 + f];
  const float bf_ = bias[f];
  #pragma unroll
  for (int q = 0; q < 8; ++q) {
    const int n = bx * 8 + q;
    const int c = cN[gb + n];
    const int sN = c >> 3, fine = c & 7;
    float xv[8], w1[8], w2[8];
    #pragma unroll
    for (int k = 0; k < 8; ++k) {
      const int r0 = sN * 8 + k;
      const int r = (r0 < 392) ? r0 : 391;          // clamp (weights 0 there)
      const int row = ord[gb + r];
      xv[k] = bf2f(xp[(gb + row) * 256 + f]);
      const bool act = (k < fine);
      w1[k] = act ? usr[gb + r] : 0.0f;
      w2[k] = act ? vsr[gb + r] : 0.0f;
    }
    float Y1 = PS1[((size_t)g * 50 + sN) * 256 + f];
    float Y2 = PS2[((size_t)g * 50 + sN) * 256 + f];
    #pragma unroll
    for (int k = 0; k < 8; ++k) {
      Y1 = fmaf(w1[k], xv[k], Y1);
      Y2 = fmaf(w2[k], xv[k], Y2);
    }
    const float num = a1[gb + n] * (T1f - Y1) + a2[gb + n] * Y2;
    const float val = eluf_(num + bf_) + bf2f(h[(gb + n) * 256 + f]);
    x2[((size_t)bb * 5120 + (size_t)rr * 392 + n) * 256 + f] = f2bf(val);
  }
}

// --------------------------------------------------------------------------
// Graph feature sums of m (one dispatch): intra partials + inter sums.
// --------------------------------------------------------------------------
__global__ __launch_bounds__(256) void sums_ab_k(const short* __restrict__ m,
    float* __restrict__ Sp, float* __restrict__ Se, int G8) {
  const int f = threadIdx.x;
  if ((int)blockIdx.x < G8) {
    const int g = blockIdx.x >> 3, ch = blockIdx.x & 7;
    const short* p = m + ((size_t)g * 392 + ch * 49) * 256 + f;
    float a0 = 0.0f, a1 = 0.0f, a2 = 0.0f, a3 = 0.0f;
    for (int c = 0; c < 48; c += 4) {
      a0 += bf2f(p[(size_t)(c + 0) * 256]);
      a1 += bf2f(p[(size_t)(c + 1) * 256]);
      a2 += bf2f(p[(size_t)(c + 2) * 256]);
      a3 += bf2f(p[(size_t)(c + 3) * 256]);
    }
    a0 += bf2f(p[(size_t)48 * 256]);
    Sp[((size_t)g * 8 + ch) * 256 + f] = (a0 + a1) + (a2 + a3);
  } else {
    const int g = blockIdx.x - G8;
    const int b = g / 392, c = g % 392;
    const short* p = m + ((size_t)(b * 13) * 392 + c) * 256 + f;
    float acc = 0.0f;
    #pragma unroll
    for (int r = 0; r < 13; ++r) acc += bf2f(p[(size_t)r * 392 * 256]);
    Se[(size_t)g * 256 + f] = acc;
  }
}

__global__ void sums_intra_fin_k(const float* __restrict__ Sp, float* __restrict__ S) {
  const int g = blockIdx.x;
  const int f = threadIdx.x;
  float acc = 0.0f;
  #pragma unroll
  for (int ch = 0; ch < 8; ++ch) acc += Sp[((size_t)g * 8 + ch) * 256 + f];
  S[(size_t)g * 256 + f] = acc;
}

// --------------------------------------------------------------------------
// BOTH h variants + attention scalars in one pass over nodes/m.
// --------------------------------------------------------------------------
__global__ void h_st_both_k(const short* __restrict__ nodes, const short* __restrict__ m,
    const float* __restrict__ Si, const float* __restrict__ Se,
    const float* __restrict__ was, const float* __restrict__ wan,
    short* __restrict__ h1, short* __restrict__ h2,
    float* __restrict__ sb1, float* __restrict__ tb1,
    float* __restrict__ sb2, float* __restrict__ tb2) {
  const int row = blockIdx.x * 8 + (threadIdx.x >> 5);
  const int f0 = (threadIdx.x & 31) * 8;
  const int g1 = row / 392;
  const int b = row / 5096;
  const int c = row % 392;
  const int g2 = b * 392 + c;
  const size_t e0 = (size_t)row * 256 + f0;
  const bf16x8 mv8 = *(const bf16x8*)(m + e0);
  const bf16x8 nv8 = *(const bf16x8*)(nodes + e0);
  const float* Sp1 = Si + (size_t)g1 * 256 + f0;
  const float* Sp2 = Se + (size_t)g2 * 256 + f0;
  bf16x8 o1, o2;
  float s1 = 0.0f, t1 = 0.0f, s2 = 0.0f, t2 = 0.0f;
  #pragma unroll
  for (int i = 0; i < 8; ++i) {
    const float mv = bf2f(mv8[i]);
    const float base = 0.1f * mv + bf2f(nv8[i]);
    const float hv1 = 0.9f * (Sp1[i] + mv) * (1.0f / 393.0f) + base;
    const float hv2 = 0.9f * (Sp2[i] + mv) * (1.0f / 14.0f) + base;
    o1[i] = f2bf(hv1);
    o2[i] = f2bf(hv2);
    const float wa = was[f0 + i], wn = wan[f0 + i];
    s1 = fmaf(hv1, wa, s1); t1 = fmaf(hv1, wn, t1);
    s2 = fmaf(hv2, wa, s2); t2 = fmaf(hv2, wn, t2);
  }
  *(bf16x8*)(h1 + e0) = o1;
  *(bf16x8*)(h2 + e0) = o2;
  #pragma unroll
  for (int off = 16; off; off >>= 1) {
    s1 += __shfl_xor(s1, off, 32); t1 += __shfl_xor(t1, off, 32);
    s2 += __shfl_xor(s2, off, 32); t2 += __shfl_xor(t2, off, 32);
  }
  if ((threadIdx.x & 31) == 0) {
    sb1[row] = s1; tb1[row] = t1;
    sb2[row] = s2; tb2[row] = t2;
  }
}

// --------------------------------------------------------------------------
// Inter attention: 13-node graphs, one block per (b,c).
// --------------------------------------------------------------------------
__global__ __launch_bounds__(256) void attn_inter_k(const short* __restrict__ xp,
    const float* __restrict__ sb, const float* __restrict__ tb,
    const short* __restrict__ h, const float* __restrict__ bias,
    short* __restrict__ x2, int B) {
  const int g = blockIdx.x;
  const int b = g / 392, c = g % 392;
  const int tid = threadIdx.x;
  __shared__ float xps[13][256];
  __shared__ float e_s[13][14];
  __shared__ float sv[13], tv[13], denom[13];
  __shared__ float tmax_s;
  for (int lin = tid; lin < 13 * 256; lin += 256) {
    const int r = lin >> 8, f = lin & 255;
    xps[r][f] = bf2f(xp[((size_t)(b * 13 + r) * 392 + c) * 256 + f]);
  }
  if (tid < 13) {
    const size_t row = (size_t)(b * 13 + tid) * 392 + c;
    sv[tid] = sb[row];
    tv[tid] = tb[row];
  }
  __syncthreads();
  if (tid == 0) {
    float mx = tv[0];
    for (int r = 1; r < 13; ++r) mx = fmaxf(mx, tv[r]);
    tmax_s = mx;
  }
  __syncthreads();
  if (tid < 169) {
    const int n = tid / 13, mm = tid % 13;
    e_s[n][mm] = __expf(leakyf_(sv[n] + tv[mm]) - leakyf_(sv[n] + tmax_s));
  }
  __syncthreads();
  if (tid < 13) {
    float d = 0.0f;
    for (int mm = 0; mm < 13; ++mm) d += e_s[tid][mm];
    denom[tid] = d;
  }
  __syncthreads();
  const int f = tid;
  for (int n = 0; n < 13; ++n) {
    float acc = 0.0f;
    #pragma unroll
    for (int mm = 0; mm < 13; ++mm) acc = fmaf(e_s[n][mm], xps[mm][f], acc);
    const float o = acc / denom[n];
    const size_t hbase = ((size_t)(b * 13 + n) * 392 + c) * 256 + f;
    x2[(((size_t)(B + b)) * 5120 + (size_t)n * 392 + c) * 256 + f] =
        f2bf(eluf_(o + bias[f]) + bf2f(h[hbase]));
  }
}

// --------------------------------------------------------------------------
// Head: BN + dense(512->200) + softmax.
// --------------------------------------------------------------------------
__global__ __launch_bounds__(256) void head_k(const float* __restrict__ xf,
    const float* __restrict__ gamma, const float* __restrict__ beta,
    const float* __restrict__ mean, const float* __restrict__ var,
    const float* __restrict__ Wd, const float* __restrict__ bd,
    float* __restrict__ out) {
  const int b = blockIdx.x;
  const int tid = threadIdx.x;
  __shared__ float xn[512];
  __shared__ float red[256];
  for (int i = tid; i < 512; i += 256) {
    const float v = xf[(size_t)b * 512 + i];
    xn[i] = (v - mean[i]) / sqrtf(var[i] + 1e-3f) * gamma[i] + beta[i];
  }
  __syncthreads();
  float logit = -1e30f;
  if (tid < 200) {
    float acc = bd[tid];
    for (int i = 0; i < 512; ++i) acc = fmaf(xn[i], Wd[(size_t)i * 200 + tid], acc);
    logit = acc;
  }
  red[tid] = logit;
  __syncthreads();
  for (int off = 128; off; off >>= 1) {
    if (tid < off) red[tid] = fmaxf(red[tid], red[tid + off]);
    __syncthreads();
  }
  const float mx = red[0];
  __syncthreads();
  const float e = (tid < 200) ? expf(logit - mx) : 0.0f;
  red[tid] = e;
  __syncthreads();
  for (int off = 128; off; off >>= 1) {
    if (tid < off) red[tid] += red[tid + off];
    __syncthreads();
  }
  const float inv = 1.0f / red[0];
  if (tid < 200) out[(size_t)b * 200 + tid] = e * inv;
}

// ---------------------------------------------------------------------------
extern "C" void kernel_launch(void* const* d_in, const int* in_sizes, int n_in,
                              void* d_out, int out_size, void* d_ws, size_t ws_size,
                              hipStream_t stream) {
  (void)n_in; (void)out_size; (void)ws_size;
  const float* base    = (const float*)d_in[0];
  const float* appnp_w = (const float*)d_in[1];
  const float* appnp_b = (const float*)d_in[2];
  const float* gat_k   = (const float*)d_in[3];
  const float* gat_as  = (const float*)d_in[4];
  const float* gat_an  = (const float*)d_in[5];
  const float* gat_b   = (const float*)d_in[6];
  const float* pf_w    = (const float*)d_in[7];
  const float* pf_b    = (const float*)d_in[8];
  const float* pa_w    = (const float*)d_in[9];
  const float* pa_b    = (const float*)d_in[10];
  const float* bn_g    = (const float*)d_in[11];
  const float* bn_be   = (const float*)d_in[12];
  const float* bn_mu   = (const float*)d_in[13];
  const float* bn_va   = (const float*)d_in[14];
  const float* dw      = (const float*)d_in[15];
  const float* db      = (const float*)d_in[16];
  float* out = (float*)d_out;

  const int B = in_sizes[0] / (49 * 2048);   // 8
  const int G = B * 13;                      // 104 intra graphs
  const int R = G * 392;                     // 40768 node rows per branch
  const int Mt = (R + 127) / 128;            // 319 row tiles
  const int Rpad = Mt * 128;                 // 40832 (A-panel slack)
  const int MP = 2 * B * 5120;               // padded pool rows (81920)

  char* ws = (char*)d_ws;
  size_t off = 0;
  auto alloc = [&](size_t bytes) -> void* {
    void* p = (void*)(ws + off);
    off += (bytes + 255) & ~(size_t)255;
    return p;
  };
  float* wtab   = (float*)alloc((size_t)13 * 2 * 49 * 4);
  short* aWhi   = (short*)alloc((size_t)256 * 256 * 2);
  short* gkhi   = (short*)alloc((size_t)256 * 256 * 2);
  short* pwcomb = (short*)alloc((size_t)1024 * 256 * 2);
  float* was    = (float*)alloc((size_t)256 * 4);
  float* wan    = (float*)alloc((size_t)256 * 4);
  short* nodes  = (short*)alloc((size_t)Rpad * 256 * 2);
  short* mbuf   = (short*)alloc((size_t)R * 256 * 2);
  short* hboth  = (short*)alloc((size_t)2 * Rpad * 256 * 2);   // [2][Rpad][256]
  short* xpboth = (short*)alloc((size_t)2 * Rpad * 256 * 2);   // [2][Rpad][256]
  short* x2buf  = (short*)alloc((size_t)MP * 256 * 2);
  float* Spart  = (float*)alloc((size_t)G * 8 * 256 * 4);
  float* Sintra = (float*)alloc((size_t)G * 256 * 4);
  float* Sinter = (float*)alloc((size_t)B * 392 * 256 * 4);
  float* sbuf   = (float*)alloc((size_t)R * 4);
  float* tbuf   = (float*)alloc((size_t)R * 4);
  float* sbuf2  = (float*)alloc((size_t)R * 4);
  float* tbuf2  = (float*)alloc((size_t)R * 4);
  unsigned short* ordb = (unsigned short*)alloc((size_t)R * 2);
  float* usrb   = (float*)alloc((size_t)R * 4);
  float* vsrb   = (float*)alloc((size_t)R * 4);
  unsigned short* cNb = (unsigned short*)alloc((size_t)R * 2);
  float* a1b    = (float*)alloc((size_t)R * 4);
  float* a2b    = (float*)alloc((size_t)R * 4);
  float* SS1    = (float*)alloc((size_t)G * 49 * 256 * 4);
  float* SS2    = (float*)alloc((size_t)G * 49 * 256 * 4);
  float* PS1    = (float*)alloc((size_t)G * 50 * 256 * 4);
  float* PS2    = (float*)alloc((size_t)G * 50 * 256 * 4);
  float* xf     = (float*)alloc((size_t)B * 512 * 4);

  short* hbuf  = hboth;
  short* hbuf2 = hboth + (size_t)Rpad * 256;
  short* xpbuf  = xpboth;
  short* xpbuf2 = xpboth + (size_t)Rpad * 256;

  hipMemsetAsync(xf, 0, (size_t)B * 512 * 4, stream);
  prep_k<<<1601, 256, 0, stream>>>(appnp_w, gat_k, pf_w, pa_w, gat_as, gat_an,
                                   aWhi, gkhi, pwcomb, wtab, was, wan);
  nodes_k<<<B * 13 * 8, 256, 0, stream>>>(base, wtab, nodes);

  // m = sigmoid(nodes @ appnp_w + b)  (shared by both branches)
  gemm_t<EP_SIG><<<dim3(Mt, 2), 256, 0, stream>>>(nodes, aWhi, R, 1 << 28,
      appnp_b, mbuf);
  sums_ab_k<<<G * 8 + B * 392, 256, 0, stream>>>(mbuf, Spart, Sinter, G * 8);
  sums_intra_fin_k<<<G, 256, 0, stream>>>(Spart, Sintra);

  // both h variants + attention scalars in one pass
  h_st_both_k<<<R / 8, 256, 0, stream>>>(nodes, mbuf, Sintra, Sinter, was, wan,
                                         hbuf, hbuf2, sbuf, tbuf, sbuf2, tbuf2);

  // setup is independent of xp; fills the queue while GEMM runs
  attn_setup_k<<<G, 256, 0, stream>>>(sbuf, tbuf, ordb, usrb, vsrb, cNb, a1b, a2b);

  // merged xp GEMM for BOTH branches: M = 2*Rpad rows
  gemm_t<EP_PLAIN><<<dim3(2 * Mt, 2), 256, 0, stream>>>(hboth, gkhi, R, Rpad,
      nullptr, xpboth);

  // ---- intra branch ----
  attn_seg_k<<<dim3(49, G), 256, 0, stream>>>(xpbuf, ordb, usrb, vsrb, SS1, SS2);
  attn_scan_k<<<G, 256, 0, stream>>>(SS1, SS2, PS1, PS2);
  attn_out_k<<<dim3(49, G), 256, 0, stream>>>(xpbuf, ordb, usrb, vsrb, cNb,
      a1b, a2b, PS1, PS2, gat_b, hbuf, x2buf);

  // ---- inter branch ----
  attn_inter_k<<<B * 392, 256, 0, stream>>>(xpbuf2, sbuf2, tbuf2, hbuf2, gat_b, x2buf, B);

  // ---- pool + head ----
  pool2_k<<<2560, 256, 0, stream>>>(x2buf, pwcomb, pf_b, pa_b, xf);
  head_k<<<B, 256, 0, stream>>>(xf, bn_g, bn_be, bn_mu, bn_va, dw, db, out);
}

// Round 19
// 355.189 us; speedup vs baseline: 1.1006x; 1.1006x over previous
//
#include <hip/hip_runtime.h>
#include <math.h>

// ---------------------------------------------------------------------------
// I2HOFI forward. B=8, 13 ROI graphs x 392 nodes (intra) / 392 x 13 (inter),
// feature 256. Weight GEMMs + pool: 128x128 LDS-tiled bf16 MFMA, K=256,
// BK=32, double-buffered LDS (1 barrier/K-step) + 2-deep register prefetch.
// Intra GAT: separable leaky-softmax O(N*d): seg-sum -> scan -> output with
// statically-unrolled masked 8-wide fine correction (no serial loop).
// Node row layout: row = (b*13 + r)*392 + c.
// x2 rows padded per (branch,b) segment: seg*5120 + within (within < 5096).
// ---------------------------------------------------------------------------

typedef __attribute__((ext_vector_type(8))) short bf16x8;
typedef __attribute__((ext_vector_type(4))) float f32x4;

#define MFMA16x32(a, b, c) __builtin_amdgcn_mfma_f32_16x16x32_bf16((a), (b), (c), 0, 0, 0)

__device__ __forceinline__ float sigmoidf_(float x) { return 1.0f / (1.0f + __expf(-x)); }
__device__ __forceinline__ float leakyf_(float x) { return x >= 0.0f ? x : 0.2f * x; }
__device__ __forceinline__ float eluf_(float x) { return x > 0.0f ? x : __expf(x) - 1.0f; }
__device__ __forceinline__ short f2bf(float f) {
  unsigned u = __builtin_bit_cast(unsigned, f);
  unsigned r = u + 0x7fffu + ((u >> 16) & 1u);
  return (short)(r >> 16);
}
__device__ __forceinline__ float bf2f(short s) {
  unsigned u = ((unsigned)(unsigned short)s) << 16;
  return __builtin_bit_cast(float, u);
}
__device__ __forceinline__ f32x4 fzero4() {
  f32x4 z;
  #pragma unroll
  for (int i = 0; i < 4; ++i) z[i] = 0.0f;
  return z;
}

// --------------------------------------------------------------------------
// prep_k: all weight preprocessing in ONE dispatch.
// --------------------------------------------------------------------------
__global__ __launch_bounds__(256) void prep_k(
    const float* __restrict__ appnp_w, const float* __restrict__ gat_k,
    const float* __restrict__ pf_w, const float* __restrict__ pa_w,
    const float* __restrict__ gat_as, const float* __restrict__ gat_an,
    short* __restrict__ aWhi, short* __restrict__ gkhi,
    short* __restrict__ pwcomb, float* __restrict__ wtab,
    float* __restrict__ was, float* __restrict__ wan) {
  const int bx = blockIdx.x;
  const int tid = threadIdx.x;
  if (bx < 512) {
    const int idx = (bx & 255) * 256 + tid;
    const int k = idx >> 8, n = idx & 255;
    const float* src = (bx < 256) ? appnp_w : gat_k;
    short* dst = (bx < 256) ? aWhi : gkhi;
    dst[(size_t)n * 256 + k] = f2bf(src[(size_t)k * 256 + n]);
  } else if (bx < 1536) {
    const int idx = (bx - 512) * 256 + tid;
    const int n = idx >> 8, k = idx & 255;
    const int p = n >> 4, i = n & 15;
    const int sc = ((p >> 1) << 4) + i;
    const float v = (p & 1) ? pa_w[(size_t)k * 512 + sc] : pf_w[(size_t)k * 512 + sc];
    pwcomb[(size_t)n * 256 + k] = f2bf(v);
  } else if (bx == 1536) {
    const int RX[12] = {0,14,28, 0,14,28, 0,14,28, 0, 0, 0};
    const int RY[12] = {0, 0, 0,14,14,14,28,28,28, 0,21, 0};
    const int RW[12] = {14,14,14,14,14,14,14,14,14,42,42,42};
    const int RH[12] = {14,14,14,14,14,14,14,14,14,21,21,42};
    for (int e = tid; e < 13 * 2 * 49; e += 256) {
      const int roi = e / 98;
      const int rest = e % 98;
      const int axis = rest / 49;
      const int o = (rest % 49) / 7;
      const int ib = rest % 7;
      float wout;
      if (roi == 12) {
        wout = (o == ib) ? 1.0f : 0.0f;
      } else {
        const int start = axis ? RX[roi] : RY[roi];
        const int len = axis ? RW[roi] : RH[roi];
        const float s = (float)len / 7.0f;
        const float oc = (o + 0.5f) * s - 0.5f;
        float wsum = 0.0f, dot = 0.0f;
        for (int j = 0; j < len; ++j) {
          float w = 1.0f - fabsf((float)j - oc) / s;
          if (w <= 0.0f) continue;
          wsum += w;
          const float ic = ((float)(start + j) + 0.5f) / 6.0f - 0.5f;
          const float fl = floorf(ic);
          const int ia = (int)fl;
          const float fr = ic - fl;
          int c0 = ia;     if (c0 < 0) c0 = 0; if (c0 > 6) c0 = 6;
          int c1 = ia + 1; if (c1 < 0) c1 = 0; if (c1 > 6) c1 = 6;
          float u = 0.0f;
          if (c0 == ib) u += 1.0f - fr;
          if (c1 == ib) u += fr;
          dot += w * u;
        }
        wout = dot / wsum;
      }
      wtab[e] = wout;
    }
  } else {
    const int w = tid >> 6, l = tid & 63;
    const int row = (bx - 1537) * 4 + w;
    const float* p = gat_k + (size_t)row * 256;
    float s = 0.0f, t = 0.0f;
    #pragma unroll
    for (int j = 0; j < 4; ++j) {
      const int o = l + j * 64;
      const float v = p[o];
      s = fmaf(v, gat_as[o], s);
      t = fmaf(v, gat_an[o], t);
    }
    #pragma unroll
    for (int off = 32; off; off >>= 1) { s += __shfl_down(s, off); t += __shfl_down(t, off); }
    if (l == 0) { was[row] = s; wan[row] = t; }
  }
}

// --------------------------------------------------------------------------
// K1: nodes (bf16) via separable 49x49 resize contraction.
// --------------------------------------------------------------------------
__global__ __launch_bounds__(256) void nodes_k(const float* __restrict__ base,
                                               const float* __restrict__ wtab,
                                               short* __restrict__ nodes) {
  const int blk = blockIdx.x;
  const int chunk = blk & 7;
  const int br = blk >> 3;
  const int r = br % 13;
  const int b = br / 13;
  const int f = threadIdx.x;
  __shared__ float W49[49][50];
  const float* wv = wtab + (r * 2 + 0) * 49;
  const float* wh = wtab + (r * 2 + 1) * 49;
  for (int e = f; e < 2401; e += 256) {
    const int o = e / 49, in = e % 49;
    W49[o][in] = wv[(o / 7) * 7 + in / 7] * wh[(o % 7) * 7 + in % 7];
  }
  __syncthreads();
  float bv[49];
  const float* bp = base + (size_t)b * 49 * 2048 + chunk * 256 + f;
  #pragma unroll
  for (int in = 0; in < 49; ++in) bv[in] = bp[(size_t)in * 2048];
  const size_t obase = ((size_t)(b * 13 + r) * 392 + chunk * 49) * 256 + f;
  for (int o = 0; o < 49; ++o) {
    float acc = 0.0f;
    #pragma unroll
    for (int in = 0; in < 49; ++in) acc = fmaf(W49[o][in], bv[in], acc);
    nodes[obase + (size_t)o * 256] = f2bf(acc);
  }
}

// --------------------------------------------------------------------------
// Tiled MFMA GEMM: 128x128 tile, K=256 (8 steps of BK=32), 4 waves (2x2).
// Double-buffered LDS, ONE barrier per K-step, register prefetch distance 2.
// Epilogues: PLAIN (2-segment via segRows) / SIG / POOL.
// --------------------------------------------------------------------------
enum { EP_PLAIN = 0, EP_SIG = 1, EP_POOL = 3 };

template <int EPI>
__global__ __launch_bounds__(256) void gemm_t(
    const short* __restrict__ A, const short* __restrict__ BT,
    const int Mvalid, const int segRows,
    const float* __restrict__ e0, const float* __restrict__ e1,
    short* __restrict__ Cs, float* __restrict__ xf) {
  const int tid = threadIdx.x;
  const int w = tid >> 6, l = tid & 63;
  const int lr = l & 15, kb = l >> 4;
  const int wr = w >> 1, wc = w & 1;

  int row0, col0, rbase = 0, bseg = 0;
  if constexpr (EPI == EP_POOL) {
    const int bid = blockIdx.x;
    const int eff = (bid & 7) * 640 + (bid >> 3);   // XCD-chunked swizzle
    const int mt = eff >> 3, ct = eff & 7;
    row0 = mt * 128; col0 = ct * 128;
    rbase = (mt % 40) * 128;
    bseg = (mt / 40) & 7;
  } else {
    row0 = blockIdx.x * 128; col0 = blockIdx.y * 128;
  }

  __shared__ short As[2][128][32];
  __shared__ short Bs[2][128][32];

  const int srow = w * 32 + (l >> 2);
  const int sso = (l & 3) * 8;
  const short* ag0 = A + (size_t)(row0 + srow) * 256 + sso;
  const short* ag1 = ag0 + (size_t)16 * 256;
  const short* bg0 = BT + (size_t)(col0 + srow) * 256 + sso;
  const short* bg1 = bg0 + (size_t)16 * 256;

  f32x4 acc[4][4];
  #pragma unroll
  for (int i = 0; i < 4; ++i)
    #pragma unroll
    for (int j = 0; j < 4; ++j) acc[i][j] = fzero4();

  auto compute = [&](const short (*Ab)[32], const short (*Bb)[32]) {
    bf16x8 va[4], vb[4];
    #pragma unroll
    for (int i = 0; i < 4; ++i) va[i] = *(const bf16x8*)&Ab[wr * 64 + i * 16 + lr][kb * 8];
    #pragma unroll
    for (int j = 0; j < 4; ++j) vb[j] = *(const bf16x8*)&Bb[wc * 64 + j * 16 + lr][kb * 8];
    #pragma unroll
    for (int i = 0; i < 4; ++i)
      #pragma unroll
      for (int j = 0; j < 4; ++j) acc[i][j] = MFMA16x32(va[i], vb[j], acc[i][j]);
  };

  bf16x8 eA0, eA1, eB0, eB1, oA0, oA1, oB0, oB1;
  eA0 = *(const bf16x8*)(ag0);       eA1 = *(const bf16x8*)(ag1);
  eB0 = *(const bf16x8*)(bg0);       eB1 = *(const bf16x8*)(bg1);
  oA0 = *(const bf16x8*)(ag0 + 32);  oA1 = *(const bf16x8*)(ag1 + 32);
  oB0 = *(const bf16x8*)(bg0 + 32);  oB1 = *(const bf16x8*)(bg1 + 32);
  *(bf16x8*)&As[0][srow][sso] = eA0; *(bf16x8*)&As[0][srow + 16][sso] = eA1;
  *(bf16x8*)&Bs[0][srow][sso] = eB0; *(bf16x8*)&Bs[0][srow + 16][sso] = eB1;
  eA0 = *(const bf16x8*)(ag0 + 64);  eA1 = *(const bf16x8*)(ag1 + 64);
  eB0 = *(const bf16x8*)(bg0 + 64);  eB1 = *(const bf16x8*)(bg1 + 64);
  __syncthreads();

  #pragma unroll
  for (int kt = 0; kt < 8; kt += 2) {
    {
      *(bf16x8*)&As[1][srow][sso] = oA0; *(bf16x8*)&As[1][srow + 16][sso] = oA1;
      *(bf16x8*)&Bs[1][srow][sso] = oB0; *(bf16x8*)&Bs[1][srow + 16][sso] = oB1;
      if (kt + 3 < 8) {
        const int ko = (kt + 3) * 32;
        oA0 = *(const bf16x8*)(ag0 + ko); oA1 = *(const bf16x8*)(ag1 + ko);
        oB0 = *(const bf16x8*)(bg0 + ko); oB1 = *(const bf16x8*)(bg1 + ko);
      }
    }
    compute(As[0], Bs[0]);
    __syncthreads();
    if (kt + 2 < 8) {
      *(bf16x8*)&As[0][srow][sso] = eA0; *(bf16x8*)&As[0][srow + 16][sso] = eA1;
      *(bf16x8*)&Bs[0][srow][sso] = eB0; *(bf16x8*)&Bs[0][srow + 16][sso] = eB1;
      if (kt + 4 < 8) {
        const int ko = (kt + 4) * 32;
        eA0 = *(const bf16x8*)(ag0 + ko); eA1 = *(const bf16x8*)(ag1 + ko);
        eB0 = *(const bf16x8*)(bg0 + ko); eB1 = *(const bf16x8*)(bg1 + ko);
      }
    }
    compute(As[1], Bs[1]);
    __syncthreads();
  }

  if constexpr (EPI == EP_PLAIN || EPI == EP_SIG) {
    #pragma unroll
    for (int j = 0; j < 4; ++j) {
      const int col = col0 + wc * 64 + j * 16 + lr;
      float bs = 0.0f;
      if constexpr (EPI == EP_SIG) bs = e0[col];
      #pragma unroll
      for (int i = 0; i < 4; ++i) {
        const int row = row0 + wr * 64 + i * 16 + kb * 4;
        #pragma unroll
        for (int r = 0; r < 4; ++r) {
          const int grow = row + r;
          const int lrow = (grow >= segRows) ? grow - segRows : grow;
          if (lrow < Mvalid) {
            float o = acc[i][j][r];
            if constexpr (EPI == EP_SIG) o = sigmoidf_(o + bs);
            Cs[(size_t)grow * 256 + col] = f2bf(o);
          }
        }
      }
    }
  } else {  // EP_POOL
    #pragma unroll
    for (int jp = 0; jp < 2; ++jp) {
      const int j = jp * 2;
      const int cg = col0 + wc * 64 + j * 16;        // feat group base
      const int realcol = ((cg >> 5) << 4) + lr;
      const float bfv = e0[realcol], bav = e1[realcol];
      float cs = 0.0f;
      #pragma unroll
      for (int i = 0; i < 4; ++i) {
        const int rl = rbase + wr * 64 + i * 16 + kb * 4;
        #pragma unroll
        for (int r = 0; r < 4; ++r) {
          if (rl + r < 5096) {
            const float fv = acc[i][j][r] + bfv;
            const float gv = acc[i][j + 1][r] + bav;
            cs += sigmoidf_(gv) * fv;
          }
        }
      }
      cs += __shfl_xor(cs, 16);
      cs += __shfl_xor(cs, 32);
      if (l < 16) atomicAdd(&xf[(size_t)bseg * 512 + realcol], cs);
    }
  }
}

// --------------------------------------------------------------------------
// Intra GAT, separable leaky-softmax (exact fp32). A: per-graph setup.
// --------------------------------------------------------------------------
__global__ __launch_bounds__(256) void attn_setup_k(
    const float* __restrict__ sb, const float* __restrict__ tb,
    unsigned short* __restrict__ ord, float* __restrict__ usr,
    float* __restrict__ vsr, unsigned short* __restrict__ cN,
    float* __restrict__ a1, float* __restrict__ a2) {
  const int g = blockIdx.x;
  const int tid = threadIdx.x;
  __shared__ float t_s[392], s_s[392];
  __shared__ float u_r[392], v_r[392];
  __shared__ float pu_s[393], pv_s[393];
  __shared__ unsigned short cn_s[392];
  __shared__ float red[256];
  const size_t gb = (size_t)g * 392;
  for (int i = tid; i < 392; i += 256) {
    t_s[i] = tb[gb + i];
    s_s[i] = sb[gb + i];
  }
  __syncthreads();
  float lm = -1e30f;
  for (int i = tid; i < 392; i += 256) lm = fmaxf(lm, t_s[i]);
  red[tid] = lm;
  __syncthreads();
  for (int off = 128; off; off >>= 1) {
    if (tid < off) red[tid] = fmaxf(red[tid], red[tid + off]);
    __syncthreads();
  }
  const float tmax = red[0];
  for (int i = tid; i < 392; i += 256) {
    const float ti = t_s[i], si = s_s[i];
    int rt = 0, c = 0;
    for (int j = 0; j < 392; ++j) {
      const float tj = t_s[j];
      rt += (int)((tj < ti) | ((tj == ti) & (j < i)));
      c  += (int)(tj < -si);
    }
    const float u = __expf(ti - tmax);
    const float v = __expf(0.2f * (ti - tmax));
    u_r[rt] = u; v_r[rt] = v;
    ord[gb + rt] = (unsigned short)i;
    usr[gb + rt] = u; vsr[gb + rt] = v;
    cn_s[i] = (unsigned short)c;
    cN[gb + i] = (unsigned short)c;
  }
  __syncthreads();
  if (tid == 0) {
    float r1 = 0.0f, r2 = 0.0f;
    for (int k = 0; k < 392; ++k) {
      pu_s[k] = r1; pv_s[k] = r2;
      r1 += u_r[k]; r2 += v_r[k];
    }
    pu_s[392] = r1; pv_s[392] = r2;
  }
  __syncthreads();
  const float U1 = pu_s[392];
  for (int i = tid; i < 392; i += 256) {
    const float z = s_s[i] + tmax;
    const float c1 = (z < 0.0f) ? __expf(0.8f * z) : 1.0f;
    const float c2 = (z < 0.0f) ? 1.0f : __expf(-0.8f * z);
    const int c = cn_s[i];
    const float den = c1 * (U1 - pu_s[c]) + c2 * pv_s[c];
    a1[gb + i] = c1 / den;
    a2[gb + i] = c2 / den;
  }
}

// B: segment sums over 8-rank segments. grid (49, G), 256 threads = features.
__global__ __launch_bounds__(256) void attn_seg_k(
    const short* __restrict__ xp, const unsigned short* __restrict__ ord,
    const float* __restrict__ usr, const float* __restrict__ vsr,
    float* __restrict__ SS1, float* __restrict__ SS2) {
  const int g = blockIdx.y, s = blockIdx.x;
  const int f = threadIdx.x;
  const size_t gb = (size_t)g * 392;
  float acc1 = 0.0f, acc2 = 0.0f;
  #pragma unroll
  for (int k = 0; k < 8; ++k) {
    const int r = s * 8 + k;
    const int row = ord[gb + r];
    const float x = bf2f(xp[(gb + row) * 256 + f]);
    acc1 = fmaf(usr[gb + r], x, acc1);
    acc2 = fmaf(vsr[gb + r], x, acc2);
  }
  SS1[((size_t)g * 49 + s) * 256 + f] = acc1;
  SS2[((size_t)g * 49 + s) * 256 + f] = acc2;
}

// C: 49-step exclusive scan -> PS[0..49] (PS[49] = total). grid G.
__global__ __launch_bounds__(256) void attn_scan_k(
    const float* __restrict__ SS1, const float* __restrict__ SS2,
    float* __restrict__ PS1, float* __restrict__ PS2) {
  const int g = blockIdx.x;
  const int f = threadIdx.x;
  float r1 = 0.0f, r2 = 0.0f;
  for (int s = 0; s < 49; ++s) {
    PS1[((size_t)g * 50 + s) * 256 + f] = r1;
    PS2[((size_t)g * 50 + s) * 256 + f] = r2;
    r1 += SS1[((size_t)g * 49 + s) * 256 + f];
    r2 += SS2[((size_t)g * 49 + s) * 256 + f];
  }
  PS1[((size_t)g * 50 + 49) * 256 + f] = r1;
  PS2[((size_t)g * 50 + 49) * 256 + f] = r2;
}

// D: outputs. grid (49, G), block 256 = features; 8 outputs per block.
// Fine correction statically unrolled to 8 masked lanes: all loads issue as
// one independent batch per output (same summation order -> identical math;
// rank index clamped for the fine==0 edge where weights are all zero).
__global__ __launch_bounds__(256) void attn_out_k(
    const short* __restrict__ xp, const unsigned short* __restrict__ ord,
    const float* __restrict__ usr, const float* __restrict__ vsr,
    const unsigned short* __restrict__ cN, const float* __restrict__ a1,
    const float* __restrict__ a2, const float* __restrict__ PS1,
    const float* __restrict__ PS2, const float* __restrict__ bias,
    const short* __restrict__ h, short* __restrict__ x2) {
  const int g = blockIdx.y, bx = blockIdx.x;
  const int f = threadIdx.x;
  const size_t gb = (size_t)g * 392;
  const int bb = g / 13, rr = g % 13;
  const float T1f = PS1[((size_t)g * 50 + 49) * 256 + f];
  const float bf_ = bias[f];
  #pragma unroll
  for (int q = 0; q < 8; ++q) {
    const int n = bx * 8 + q;
    const int c = cN[gb + n];
    const int sN = c >> 3, fine = c & 7;
    float xv[8], w1[8], w2[8];
    #pragma unroll
    for (int k = 0; k < 8; ++k) {
      const int r0 = sN * 8 + k;
      const int r = (r0 < 392) ? r0 : 391;          // clamp (weights 0 there)
      const int row = ord[gb + r];
      xv[k] = bf2f(xp[(gb + row) * 256 + f]);
      const bool act = (k < fine);
      w1[k] = act ? usr[gb + r] : 0.0f;
      w2[k] = act ? vsr[gb + r] : 0.0f;
    }
    float Y1 = PS1[((size_t)g * 50 + sN) * 256 + f];
    float Y2 = PS2[((size_t)g * 50 + sN) * 256 + f];
    #pragma unroll
    for (int k = 0; k < 8; ++k) {
      Y1 = fmaf(w1[k], xv[k], Y1);
      Y2 = fmaf(w2[k], xv[k], Y2);
    }
    const float num = a1[gb + n] * (T1f - Y1) + a2[gb + n] * Y2;
    const float val = eluf_(num + bf_) + bf2f(h[(gb + n) * 256 + f]);
    x2[((size_t)bb * 5120 + (size_t)rr * 392 + n) * 256 + f] = f2bf(val);
  }
}

// --------------------------------------------------------------------------
// Graph feature sums of m (one dispatch): intra partials + inter sums.
// --------------------------------------------------------------------------
__global__ __launch_bounds__(256) void sums_ab_k(const short* __restrict__ m,
    float* __restrict__ Sp, float* __restrict__ Se, int G8) {
  const int f = threadIdx.x;
  if ((int)blockIdx.x < G8) {
    const int g = blockIdx.x >> 3, ch = blockIdx.x & 7;
    const short* p = m + ((size_t)g * 392 + ch * 49) * 256 + f;
    float a0 = 0.0f, a1 = 0.0f, a2 = 0.0f, a3 = 0.0f;
    for (int c = 0; c < 48; c += 4) {
      a0 += bf2f(p[(size_t)(c + 0) * 256]);
      a1 += bf2f(p[(size_t)(c + 1) * 256]);
      a2 += bf2f(p[(size_t)(c + 2) * 256]);
      a3 += bf2f(p[(size_t)(c + 3) * 256]);
    }
    a0 += bf2f(p[(size_t)48 * 256]);
    Sp[((size_t)g * 8 + ch) * 256 + f] = (a0 + a1) + (a2 + a3);
  } else {
    const int g = blockIdx.x - G8;
    const int b = g / 392, c = g % 392;
    const short* p = m + ((size_t)(b * 13) * 392 + c) * 256 + f;
    float acc = 0.0f;
    #pragma unroll
    for (int r = 0; r < 13; ++r) acc += bf2f(p[(size_t)r * 392 * 256]);
    Se[(size_t)g * 256 + f] = acc;
  }
}

__global__ void sums_intra_fin_k(const float* __restrict__ Sp, float* __restrict__ S) {
  const int g = blockIdx.x;
  const int f = threadIdx.x;
  float acc = 0.0f;
  #pragma unroll
  for (int ch = 0; ch < 8; ++ch) acc += Sp[((size_t)g * 8 + ch) * 256 + f];
  S[(size_t)g * 256 + f] = acc;
}

// --------------------------------------------------------------------------
// BOTH h variants + attention scalars in one pass over nodes/m.
// --------------------------------------------------------------------------
__global__ void h_st_both_k(const short* __restrict__ nodes, const short* __restrict__ m,
    const float* __restrict__ Si, const float* __restrict__ Se,
    const float* __restrict__ was, const float* __restrict__ wan,
    short* __restrict__ h1, short* __restrict__ h2,
    float* __restrict__ sb1, float* __restrict__ tb1,
    float* __restrict__ sb2, float* __restrict__ tb2) {
  const int row = blockIdx.x * 8 + (threadIdx.x >> 5);
  const int f0 = (threadIdx.x & 31) * 8;
  const int g1 = row / 392;
  const int b = row / 5096;
  const int c = row % 392;
  const int g2 = b * 392 + c;
  const size_t e0 = (size_t)row * 256 + f0;
  const bf16x8 mv8 = *(const bf16x8*)(m + e0);
  const bf16x8 nv8 = *(const bf16x8*)(nodes + e0);
  const float* Sp1 = Si + (size_t)g1 * 256 + f0;
  const float* Sp2 = Se + (size_t)g2 * 256 + f0;
  bf16x8 o1, o2;
  float s1 = 0.0f, t1 = 0.0f, s2 = 0.0f, t2 = 0.0f;
  #pragma unroll
  for (int i = 0; i < 8; ++i) {
    const float mv = bf2f(mv8[i]);
    const float base = 0.1f * mv + bf2f(nv8[i]);
    const float hv1 = 0.9f * (Sp1[i] + mv) * (1.0f / 393.0f) + base;
    const float hv2 = 0.9f * (Sp2[i] + mv) * (1.0f / 14.0f) + base;
    o1[i] = f2bf(hv1);
    o2[i] = f2bf(hv2);
    const float wa = was[f0 + i], wn = wan[f0 + i];
    s1 = fmaf(hv1, wa, s1); t1 = fmaf(hv1, wn, t1);
    s2 = fmaf(hv2, wa, s2); t2 = fmaf(hv2, wn, t2);
  }
  *(bf16x8*)(h1 + e0) = o1;
  *(bf16x8*)(h2 + e0) = o2;
  #pragma unroll
  for (int off = 16; off; off >>= 1) {
    s1 += __shfl_xor(s1, off, 32); t1 += __shfl_xor(t1, off, 32);
    s2 += __shfl_xor(s2, off, 32); t2 += __shfl_xor(t2, off, 32);
  }
  if ((threadIdx.x & 31) == 0) {
    sb1[row] = s1; tb1[row] = t1;
    sb2[row] = s2; tb2[row] = t2;
  }
}

// --------------------------------------------------------------------------
// Inter attention: 13-node graphs, one block per (b,c).
// --------------------------------------------------------------------------
__global__ __launch_bounds__(256) void attn_inter_k(const short* __restrict__ xp,
    const float* __restrict__ sb, const float* __restrict__ tb,
    const short* __restrict__ h, const float* __restrict__ bias,
    short* __restrict__ x2, int B) {
  const int g = blockIdx.x;
  const int b = g / 392, c = g % 392;
  const int tid = threadIdx.x;
  __shared__ float xps[13][256];
  __shared__ float e_s[13][14];
  __shared__ float sv[13], tv[13], denom[13];
  __shared__ float tmax_s;
  for (int lin = tid; lin < 13 * 256; lin += 256) {
    const int r = lin >> 8, f = lin & 255;
    xps[r][f] = bf2f(xp[((size_t)(b * 13 + r) * 392 + c) * 256 + f]);
  }
  if (tid < 13) {
    const size_t row = (size_t)(b * 13 + tid) * 392 + c;
    sv[tid] = sb[row];
    tv[tid] = tb[row];
  }
  __syncthreads();
  if (tid == 0) {
    float mx = tv[0];
    for (int r = 1; r < 13; ++r) mx = fmaxf(mx, tv[r]);
    tmax_s = mx;
  }
  __syncthreads();
  if (tid < 169) {
    const int n = tid / 13, mm = tid % 13;
    e_s[n][mm] = __expf(leakyf_(sv[n] + tv[mm]) - leakyf_(sv[n] + tmax_s));
  }
  __syncthreads();
  if (tid < 13) {
    float d = 0.0f;
    for (int mm = 0; mm < 13; ++mm) d += e_s[tid][mm];
    denom[tid] = d;
  }
  __syncthreads();
  const int f = tid;
  for (int n = 0; n < 13; ++n) {
    float acc = 0.0f;
    #pragma unroll
    for (int mm = 0; mm < 13; ++mm) acc = fmaf(e_s[n][mm], xps[mm][f], acc);
    const float o = acc / denom[n];
    const size_t hbase = ((size_t)(b * 13 + n) * 392 + c) * 256 + f;
    x2[(((size_t)(B + b)) * 5120 + (size_t)n * 392 + c) * 256 + f] =
        f2bf(eluf_(o + bias[f]) + bf2f(h[hbase]));
  }
}

// --------------------------------------------------------------------------
// Head: BN + dense(512->200) + softmax.
// --------------------------------------------------------------------------
__global__ __launch_bounds__(256) void head_k(const float* __restrict__ xf,
    const float* __restrict__ gamma, const float* __restrict__ beta,
    const float* __restrict__ mean, const float* __restrict__ var,
    const float* __restrict__ Wd, const float* __restrict__ bd,
    float* __restrict__ out) {
  const int b = blockIdx.x;
  const int tid = threadIdx.x;
  __shared__ float xn[512];
  __shared__ float red[256];
  for (int i = tid; i < 512; i += 256) {
    const float v = xf[(size_t)b * 512 + i];
    xn[i] = (v - mean[i]) / sqrtf(var[i] + 1e-3f) * gamma[i] + beta[i];
  }
  __syncthreads();
  float logit = -1e30f;
  if (tid < 200) {
    float acc = bd[tid];
    for (int i = 0; i < 512; ++i) acc = fmaf(xn[i], Wd[(size_t)i * 200 + tid], acc);
    logit = acc;
  }
  red[tid] = logit;
  __syncthreads();
  for (int off = 128; off; off >>= 1) {
    if (tid < off) red[tid] = fmaxf(red[tid], red[tid + off]);
    __syncthreads();
  }
  const float mx = red[0];
  __syncthreads();
  const float e = (tid < 200) ? expf(logit - mx) : 0.0f;
  red[tid] = e;
  __syncthreads();
  for (int off = 128; off; off >>= 1) {
    if (tid < off) red[tid] += red[tid + off];
    __syncthreads();
  }
  const float inv = 1.0f / red[0];
  if (tid < 200) out[(size_t)b * 200 + tid] = e * inv;
}

// ---------------------------------------------------------------------------
extern "C" void kernel_launch(void* const* d_in, const int* in_sizes, int n_in,
                              void* d_out, int out_size, void* d_ws, size_t ws_size,
                              hipStream_t stream) {
  (void)n_in; (void)out_size; (void)ws_size;
  const float* base    = (const float*)d_in[0];
  const float* appnp_w = (const float*)d_in[1];
  const float* appnp_b = (const float*)d_in[2];
  const float* gat_k   = (const float*)d_in[3];
  const float* gat_as  = (const float*)d_in[4];
  const float* gat_an  = (const float*)d_in[5];
  const float* gat_b   = (const float*)d_in[6];
  const float* pf_w    = (const float*)d_in[7];
  const float* pf_b    = (const float*)d_in[8];
  const float* pa_w    = (const float*)d_in[9];
  const float* pa_b    = (const float*)d_in[10];
  const float* bn_g    = (const float*)d_in[11];
  const float* bn_be   = (const float*)d_in[12];
  const float* bn_mu   = (const float*)d_in[13];
  const float* bn_va   = (const float*)d_in[14];
  const float* dw      = (const float*)d_in[15];
  const float* db      = (const float*)d_in[16];
  float* out = (float*)d_out;

  const int B = in_sizes[0] / (49 * 2048);   // 8
  const int G = B * 13;                      // 104 intra graphs
  const int R = G * 392;                     // 40768 node rows per branch
  const int Mt = (R + 127) / 128;            // 319 row tiles
  const int Rpad = Mt * 128;                 // 40832 (A-panel slack)
  const int MP = 2 * B * 5120;               // padded pool rows (81920)

  char* ws = (char*)d_ws;
  size_t off = 0;
  auto alloc = [&](size_t bytes) -> void* {
    void* p = (void*)(ws + off);
    off += (bytes + 255) & ~(size_t)255;
    return p;
  };
  float* wtab   = (float*)alloc((size_t)13 * 2 * 49 * 4);
  short* aWhi   = (short*)alloc((size_t)256 * 256 * 2);
  short* gkhi   = (short*)alloc((size_t)256 * 256 * 2);
  short* pwcomb = (short*)alloc((size_t)1024 * 256 * 2);
  float* was    = (float*)alloc((size_t)256 * 4);
  float* wan    = (float*)alloc((size_t)256 * 4);
  short* nodes  = (short*)alloc((size_t)Rpad * 256 * 2);
  short* mbuf   = (short*)alloc((size_t)R * 256 * 2);
  short* hboth  = (short*)alloc((size_t)2 * Rpad * 256 * 2);   // [2][Rpad][256]
  short* xpboth = (short*)alloc((size_t)2 * Rpad * 256 * 2);   // [2][Rpad][256]
  short* x2buf  = (short*)alloc((size_t)MP * 256 * 2);
  float* Spart  = (float*)alloc((size_t)G * 8 * 256 * 4);
  float* Sintra = (float*)alloc((size_t)G * 256 * 4);
  float* Sinter = (float*)alloc((size_t)B * 392 * 256 * 4);
  float* sbuf   = (float*)alloc((size_t)R * 4);
  float* tbuf   = (float*)alloc((size_t)R * 4);
  float* sbuf2  = (float*)alloc((size_t)R * 4);
  float* tbuf2  = (float*)alloc((size_t)R * 4);
  unsigned short* ordb = (unsigned short*)alloc((size_t)R * 2);
  float* usrb   = (float*)alloc((size_t)R * 4);
  float* vsrb   = (float*)alloc((size_t)R * 4);
  unsigned short* cNb = (unsigned short*)alloc((size_t)R * 2);
  float* a1b    = (float*)alloc((size_t)R * 4);
  float* a2b    = (float*)alloc((size_t)R * 4);
  float* SS1    = (float*)alloc((size_t)G * 49 * 256 * 4);
  float* SS2    = (float*)alloc((size_t)G * 49 * 256 * 4);
  float* PS1    = (float*)alloc((size_t)G * 50 * 256 * 4);
  float* PS2    = (float*)alloc((size_t)G * 50 * 256 * 4);
  float* xf     = (float*)alloc((size_t)B * 512 * 4);

  short* hbuf  = hboth;
  short* hbuf2 = hboth + (size_t)Rpad * 256;
  short* xpbuf  = xpboth;
  short* xpbuf2 = xpboth + (size_t)Rpad * 256;

  hipMemsetAsync(xf, 0, (size_t)B * 512 * 4, stream);
  prep_k<<<1601, 256, 0, stream>>>(appnp_w, gat_k, pf_w, pa_w, gat_as, gat_an,
                                   aWhi, gkhi, pwcomb, wtab, was, wan);
  nodes_k<<<B * 13 * 8, 256, 0, stream>>>(base, wtab, nodes);

  // m = sigmoid(nodes @ appnp_w + b)  (shared by both branches)
  gemm_t<EP_SIG><<<dim3(Mt, 2), 256, 0, stream>>>(nodes, aWhi, R, 1 << 28,
      appnp_b, nullptr, mbuf, nullptr);
  sums_ab_k<<<G * 8 + B * 392, 256, 0, stream>>>(mbuf, Spart, Sinter, G * 8);
  sums_intra_fin_k<<<G, 256, 0, stream>>>(Spart, Sintra);

  // both h variants + attention scalars in one pass
  h_st_both_k<<<R / 8, 256, 0, stream>>>(nodes, mbuf, Sintra, Sinter, was, wan,
                                         hbuf, hbuf2, sbuf, tbuf, sbuf2, tbuf2);

  // setup is independent of xp; fills the queue while GEMM runs
  attn_setup_k<<<G, 256, 0, stream>>>(sbuf, tbuf, ordb, usrb, vsrb, cNb, a1b, a2b);

  // merged xp GEMM for BOTH branches: M = 2*Rpad rows
  gemm_t<EP_PLAIN><<<dim3(2 * Mt, 2), 256, 0, stream>>>(hboth, gkhi, R, Rpad,
      nullptr, nullptr, xpboth, nullptr);

  // ---- intra branch ----
  attn_seg_k<<<dim3(49, G), 256, 0, stream>>>(xpbuf, ordb, usrb, vsrb, SS1, SS2);
  attn_scan_k<<<G, 256, 0, stream>>>(SS1, SS2, PS1, PS2);
  attn_out_k<<<dim3(49, G), 256, 0, stream>>>(xpbuf, ordb, usrb, vsrb, cNb,
      a1b, a2b, PS1, PS2, gat_b, hbuf, x2buf);

  // ---- inter branch ----
  attn_inter_k<<<B * 392, 256, 0, stream>>>(xpbuf2, sbuf2, tbuf2, hbuf2, gat_b, x2buf, B);

  // ---- pool + head ----
  gemm_t<EP_POOL><<<5120, 256, 0, stream>>>(x2buf, pwcomb, 0, 0,
      pf_b, pa_b, nullptr, xf);
  head_k<<<B, 256, 0, stream>>>(xf, bn_g, bn_be, bn_mu, bn_va, dw, db, out);
}